// Round 4
// baseline (3222.240 us; speedup 1.0000x reference)
//
#include <hip/hip_runtime.h>
#include <stdint.h>

#define NB    32
#define NCI   256        // x channels (conv in = 257 with noise plane)
#define NHC   128
#define HS    56
#define HWS   3136       // 56*56
#define NELEM 12845056   // 32*128*3136
#define CHUNK 401408     // 128*3136 (one batch of h)
#define NPOS  100352     // 32*3136
#define OHS   112
#define OUTSZ 102760448  // 32*256*112*112
#define WT_SZ 296064     // 257*9*128
#define GP_SZ 4194304    // 256*16384

// BEC mask bit-stream layout:
//  1 = jax threefry_partitionable (default since jax 0.4.30): per flat index j,
//      counter64 = j -> threefry2x32(key, (0, j)), 32-bit word = o0 ^ o1.
//  2 = partitionable, word = o0 (block>>32).  3 = partitionable, word = o1.
//  0 = legacy split-iota layout (tested rounds 2-3: absmax 0.890625 -> wrong).
#define MASK_SCHEME 1

// ---------------- threefry2x32, key = (0, 42) (jax.random.key(42)) -------------
__device__ __forceinline__ void threefry_0_42(uint32_t x0, uint32_t x1,
                                              uint32_t& o0, uint32_t& o1) {
  const uint32_t ks0 = 0u, ks1 = 42u;
  const uint32_t ks2 = 0x1BD11BDAu ^ ks0 ^ ks1;
  x0 += ks0; x1 += ks1;
#define TFR(r) { x0 += x1; x1 = (x1 << (r)) | (x1 >> (32 - (r))); x1 ^= x0; }
  TFR(13) TFR(15) TFR(26) TFR(6)   x0 += ks1; x1 += ks2 + 1u;
  TFR(17) TFR(29) TFR(16) TFR(24)  x0 += ks2; x1 += ks0 + 2u;
  TFR(13) TFR(15) TFR(26) TFR(6)   x0 += ks0; x1 += ks1 + 3u;
  TFR(17) TFR(29) TFR(16) TFR(24)  x0 += ks1; x1 += ks2 + 4u;
  TFR(13) TFR(15) TFR(26) TFR(6)   x0 += ks2; x1 += ks0 + 5u;
#undef TFR
  o0 = x0; o1 = x1;
}

__device__ __forceinline__ const float* hq_cbase(const float* A, const float* B, int b) {
  return (b == 31) ? B : (A + (size_t)b * CHUNK);
}

// ---------------- weight transpose: w1[co][ci][k] -> wT[ci][k][co] --------------
__global__ __launch_bounds__(256) void k_wprep(const float* __restrict__ w1,
                                               float* __restrict__ wT) {
  int i = blockIdx.x * 256 + threadIdx.x;
  if (i < WT_SZ) {
    int ci = i / 1152;          // 9*128
    int r  = i - ci * 1152;
    int k  = r >> 7;
    int co = r & 127;
    wT[i] = w1[(co * 257 + ci) * 9 + k];
  }
}

// ---------------- conv1: 3x3 s1 p1, 257 -> 128 ch, f64 accumulation -------------
// f32*f32 products are exact in f64; accumulation error ~1e-15 -> the quantizer
// downstream sees a trajectory matching a f64 reference to ~1e-13.
__global__ __launch_bounds__(256) void k_conv1(
    const float* __restrict__ x, const float* __restrict__ noise_u,
    const float* __restrict__ wT, const float* __restrict__ b1,
    double* __restrict__ hpre) {
  __shared__ double patch[16][10][10];  // 12.8 KB
  __shared__ float  wl[16][9][64];      // 36.9 KB
  const int tile = blockIdx.x;          // 0..48  (7x7 tiles of 8x8)
  const int cc0  = blockIdx.y << 6;     // co base (0 or 64)
  const int b    = blockIdx.z;
  const int ty0 = (tile / 7) * 8, tx0 = (tile % 7) * 8;
  const int tid = threadIdx.x;
  const int pg = tid & 15, cg = tid >> 4;
  const int py0 = (pg >> 2) << 1, px0 = (pg & 3) << 1;
  const double nf = (double)noise_u[0] * 0.5;

  double acc[4][4];
#pragma unroll
  for (int i = 0; i < 4; ++i)
#pragma unroll
    for (int j = 0; j < 4; ++j) acc[i][j] = 0.0;

  for (int ch = 0; ch < 17; ++ch) {
    const int cb = ch << 4;
    for (int i = tid; i < 1600; i += 256) {
      const int ci_l = i / 100;
      const int r = i - ci_l * 100;
      const int py = r / 10, px = r - py * 10;
      const int gy = ty0 - 1 + py, gx = tx0 - 1 + px;
      const int ci = cb + ci_l;
      double v = 0.0;
      if (gy >= 0 && gy < HS && gx >= 0 && gx < HS) {
        if (ci < NCI) v = (double)x[((b * NCI + ci) * HS + gy) * HS + gx];
        else if (ci == NCI) v = nf;
      }
      patch[ci_l][py][px] = v;
    }
    for (int i = tid; i < 9216; i += 256) {
      const int ci_l = i / 576;
      const int r = i - ci_l * 576;
      const int k = r >> 6, col = r & 63;
      const int ci = cb + ci_l;
      wl[ci_l][k][col] = (ci < 257) ? wT[(ci * 9 + k) * 128 + cc0 + col] : 0.0f;
    }
    __syncthreads();
    for (int ci_l = 0; ci_l < 16; ++ci_l) {
#pragma unroll
      for (int k = 0; k < 9; ++k) {
        const int ky = k / 3, kx = k - ky * 3;
        const float4 wv = *(const float4*)&wl[ci_l][k][cg << 2];
        const double w0 = (double)wv.x, w1_ = (double)wv.y;
        const double w2 = (double)wv.z, w3 = (double)wv.w;
        const double i00 = patch[ci_l][py0 + ky][px0 + kx];
        const double i01 = patch[ci_l][py0 + ky][px0 + kx + 1];
        const double i10 = patch[ci_l][py0 + ky + 1][px0 + kx];
        const double i11 = patch[ci_l][py0 + ky + 1][px0 + kx + 1];
        acc[0][0] += w0 * i00; acc[0][1] += w0 * i01; acc[0][2] += w0 * i10; acc[0][3] += w0 * i11;
        acc[1][0] += w1_ * i00; acc[1][1] += w1_ * i01; acc[1][2] += w1_ * i10; acc[1][3] += w1_ * i11;
        acc[2][0] += w2 * i00; acc[2][1] += w2 * i01; acc[2][2] += w2 * i10; acc[2][3] += w2 * i11;
        acc[3][0] += w3 * i00; acc[3][1] += w3 * i01; acc[3][2] += w3 * i10; acc[3][3] += w3 * i11;
      }
    }
    __syncthreads();
  }
#pragma unroll
  for (int c = 0; c < 4; ++c) {
    const int co = cc0 + (cg << 2) + c;
    const double bias = (double)b1[co];
#pragma unroll
    for (int p = 0; p < 4; ++p) {
      const int oy = ty0 + py0 + (p >> 1), ox = tx0 + px0 + (p & 1);
      hpre[((b * NHC + co) * HS + oy) * HS + ox] = acc[c][p] + bias;
    }
  }
}

// ---------------- BN1 batch stats -> affine coeffs (all f64) --------------------
__global__ __launch_bounds__(256) void k_bn1stats(
    const double* __restrict__ hpre, const float* __restrict__ g1,
    const float* __restrict__ beta1, double* __restrict__ a1, double* __restrict__ c1) {
  __shared__ double rs[256], rs2[256];
  const int co = blockIdx.x, tid = threadIdx.x;
  double s = 0.0, s2 = 0.0;
  for (int b = 0; b < NB; ++b) {
    const double* p = hpre + (size_t)(b * NHC + co) * HWS;
    for (int i = tid; i < HWS; i += 256) {
      const double v = p[i];
      s += v; s2 += v * v;
    }
  }
  rs[tid] = s; rs2[tid] = s2;
  __syncthreads();
  for (int off = 128; off; off >>= 1) {
    if (tid < off) { rs[tid] += rs[tid + off]; rs2[tid] += rs2[tid + off]; }
    __syncthreads();
  }
  if (tid == 0) {
    const double m = rs[0] / (double)NPOS;
    const double var = rs2[0] / (double)NPOS - m * m;
    const double a = (double)g1[co] / sqrt(var + 1e-5);
    a1[co] = a;
    c1[co] = (double)beta1[co] - m * a;
  }
}

// ---------------- BN + sigmoid + quantize (f64) + exact BEC mask ----------------
__global__ __launch_bounds__(256) void k_bnsig(
    const double* __restrict__ hpre, const double* __restrict__ a1,
    const double* __restrict__ c1, const float* __restrict__ noise_u,
    float* __restrict__ hqA, float* __restrict__ hqB) {
  const int b = blockIdx.y;
  const unsigned off = blockIdx.x * 256u + threadIdx.x;   // < CHUNK (grid exact)
  const unsigned e = (unsigned)b * (unsigned)CHUNK + off;
  const float p = noise_u[0] * 0.5f;     // exact (mul by 0.5)
  const float qf = 1.0f - p;             // bit-exact jax f32 threshold
  const int co = (int)(off / 3136u);
  const double z = hpre[e] * a1[co] + c1[co];
  const double s = 1.0 / (1.0 + exp(-z));
  const double v = rint(s * 256.0);      // jnp.round: half-to-even; *256 exact
  const unsigned xb = ((unsigned)(long long)v) & 255u;   // % 256 wraparound
  unsigned mask = 0u;
#if MASK_SCHEME == 0
#pragma unroll
  for (unsigned bb = 0; bb < 4u; ++bb) {
    uint32_t o0, o1;
    threefry_0_42(bb * 12845056u + e, (bb + 4u) * 12845056u + e, o0, o1);
    const float u0 = __uint_as_float((o0 >> 9) | 0x3f800000u) - 1.0f;
    const float u1 = __uint_as_float((o1 >> 9) | 0x3f800000u) - 1.0f;
    if (u0 < qf) mask |= (1u << bb);
    if (u1 < qf) mask |= (1u << (bb + 4u));
  }
#else
  // partitionable: flat index j = plane*NELEM + e (< 2^32 here, so hi word 0);
  // 32-bit word folded from the 2x32 block of counter j.
#pragma unroll
  for (unsigned bb = 0; bb < 8u; ++bb) {
    uint32_t o0, o1;
    threefry_0_42(0u, bb * 12845056u + e, o0, o1);
#if MASK_SCHEME == 1
    const uint32_t bits = o0 ^ o1;
#elif MASK_SCHEME == 2
    const uint32_t bits = o0;
#else
    const uint32_t bits = o1;
#endif
    const float u = __uint_as_float((bits >> 9) | 0x3f800000u) - 1.0f;
    if (u < qf) mask |= (1u << bb);
  }
#endif
  float* dst = (b == 31) ? hqB : (hqA + (size_t)b * CHUNK);
  dst[off] = (float)(((double)(xb & mask) + (255.0 - (double)mask) * 0.5) / 255.0);
}

// ---------------- channel sums of h_q (for BN2 analytic stats) ------------------
__global__ __launch_bounds__(256) void k_meanh(const float* __restrict__ hqA,
                                               const float* __restrict__ hqB,
                                               double* __restrict__ Sh) {
  __shared__ double rs[256];
  const int co = blockIdx.x, tid = threadIdx.x;
  double s = 0.0;
  for (int b = 0; b < NB; ++b) {
    const float* p = hq_cbase(hqA, hqB, b) + (size_t)co * HWS;
    for (int i = tid; i < HWS; i += 256) s += (double)p[i];
  }
  rs[tid] = s;
  __syncthreads();
  for (int off = 128; off; off >>= 1) {
    if (tid < off) rs[tid] += rs[tid + off];
    __syncthreads();
  }
  if (tid == 0) Sh[co] = rs[0];
}

// ---------------- Gram matrix partials: G = sum_pos h h^T -----------------------
__global__ __launch_bounds__(256) void k_gram(const float* __restrict__ hqA,
                                              const float* __restrict__ hqB,
                                              float* __restrict__ gp) {
  __shared__ float ht[64][132];   // [pos][ci], padded
  const int tid = threadIdx.x;
  const int ci0 = (tid >> 4) << 3, cj0 = (tid & 15) << 3;
  float acc[8][8];
#pragma unroll
  for (int i = 0; i < 8; ++i)
#pragma unroll
    for (int j = 0; j < 8; ++j) acc[i][j] = 0.0f;

  for (int ch = blockIdx.x; ch < 1568; ch += 256) {   // 1568 = 100352/64
    const int b = ch / 49;
    const int sp0 = (ch - b * 49) << 6;
    const float* hb = hq_cbase(hqA, hqB, b);
    for (int i = tid; i < 8192; i += 256) {
      const int ci = i >> 6, pp = i & 63;
      ht[pp][ci] = hb[(size_t)ci * HWS + sp0 + pp];
    }
    __syncthreads();
    for (int k = 0; k < 64; ++k) {
      const float4 a0 = *(const float4*)&ht[k][ci0];
      const float4 a1v = *(const float4*)&ht[k][ci0 + 4];
      const float4 b0 = *(const float4*)&ht[k][cj0];
      const float4 b1v = *(const float4*)&ht[k][cj0 + 4];
      const float av[8] = {a0.x, a0.y, a0.z, a0.w, a1v.x, a1v.y, a1v.z, a1v.w};
      const float bv[8] = {b0.x, b0.y, b0.z, b0.w, b1v.x, b1v.y, b1v.z, b1v.w};
#pragma unroll
      for (int ii = 0; ii < 8; ++ii)
#pragma unroll
        for (int jj = 0; jj < 8; ++jj) acc[ii][jj] += av[ii] * bv[jj];
    }
    __syncthreads();
  }
  float* dst = gp + (size_t)blockIdx.x * 16384;
#pragma unroll
  for (int ii = 0; ii < 8; ++ii)
#pragma unroll
    for (int jj = 0; jj < 8; ++jj)
      dst[(ci0 + ii) * 128 + cj0 + jj] = acc[ii][jj];
}

__global__ __launch_bounds__(256) void k_gram_reduce(const float* __restrict__ gp,
                                                     double* __restrict__ G) {
  const int g = blockIdx.x * 256 + threadIdx.x;   // 16384
  double s = 0.0;
  for (int p = 0; p < 256; ++p) s += (double)gp[(size_t)p * 16384 + g];
  G[g] = s;
}

// ---------------- BN2 analytic stats -> affine coeffs ---------------------------
__global__ __launch_bounds__(256) void k_bn2coef(
    const float* __restrict__ w4, const float* __restrict__ b4,
    const float* __restrict__ g2, const float* __restrict__ beta2,
    const double* __restrict__ G, const double* __restrict__ Sh,
    float* __restrict__ a2, float* __restrict__ c2b) {
  __shared__ float wq[4][128];
  __shared__ double red[8][128];
  const int co = blockIdx.x, tid = threadIdx.x;
  for (int i = tid; i < 512; i += 256) {
    const int ci = i >> 2, q = i & 3;
    wq[q][ci] = w4[ci * 1024 + (co << 2) + q];
  }
  __syncthreads();
  if (tid < 128) {
    const int ci = tid;
    double rd0 = 0, rd1 = 0, rd2 = 0, rd3 = 0;
    for (int cj = 0; cj < 128; ++cj) {
      const double g = G[cj * 128 + ci];   // G is bitwise symmetric; coalesced read
      rd0 += g * (double)wq[0][cj];
      rd1 += g * (double)wq[1][cj];
      rd2 += g * (double)wq[2][cj];
      rd3 += g * (double)wq[3][cj];
    }
    const double w0 = (double)wq[0][ci], w1_ = (double)wq[1][ci];
    const double w2 = (double)wq[2][ci], w3 = (double)wq[3][ci];
    red[0][ci] = w0 * rd0; red[1][ci] = w1_ * rd1;
    red[2][ci] = w2 * rd2; red[3][ci] = w3 * rd3;
    const double sh = Sh[ci];
    red[4][ci] = w0 * sh; red[5][ci] = w1_ * sh;
    red[6][ci] = w2 * sh; red[7][ci] = w3 * sh;
  }
  __syncthreads();
  if (tid == 0) {
    double S2[4], S1[4];
    for (int q = 0; q < 4; ++q) {
      double t = 0, t1 = 0;
      for (int ci = 0; ci < 128; ++ci) { t += red[q][ci]; t1 += red[4 + q][ci]; }
      S2[q] = t; S1[q] = t1;
    }
    const double Pd = (double)NPOS;
    const double bb = (double)b4[co];
    double m2 = 0, e2 = 0;
    for (int q = 0; q < 4; ++q) {
      const double s1 = S1[q] / Pd;
      m2 += bb + s1;
      e2 += bb * bb + 2.0 * bb * s1 + S2[q] / Pd;
    }
    m2 *= 0.25; e2 *= 0.25;
    const double v2 = e2 - m2 * m2;          // biased variance, matches jnp.var
    const double a = (double)g2[co] / sqrt(v2 + 1e-5);
    const double c = (double)beta2[co] - m2 * a;
    a2[co] = (float)a;
    c2b[co] = (float)(c + bb * a);           // fold +b4 into the shift
  }
}

// ---------------- deconv (4x 1x1 GEMM) + BN2 + relu -> output -------------------
__global__ __launch_bounds__(256) void k_deconv(
    const float* __restrict__ hqA, const float* __restrict__ hqB,
    const float* __restrict__ w4,
    const float* __restrict__ a2, const float* __restrict__ c2b,
    float* __restrict__ out, int b0) {
  __shared__ float4 wl4[128][16];   // [ci][co_local] = (w00,w01,w10,w11), 32 KB
  const int pc = blockIdx.x;        // 0..48 position chunk (64 pos)
  const int cobase = blockIdx.y << 4;
  const int b = b0 + blockIdx.z;
  const int sp0 = pc << 6;
  const int tid = threadIdx.x;
  const int pg = tid & 15, cg = tid >> 4;

  for (int i = tid; i < 2048; i += 256) {
    const int ci = i >> 4, col = i & 15;
    wl4[ci][col] = *(const float4*)&w4[ci * 1024 + ((cobase + col) << 2)];
  }
  __syncthreads();

  float acc[2][2][4];
#pragma unroll
  for (int di = 0; di < 2; ++di)
#pragma unroll
    for (int dj = 0; dj < 2; ++dj)
#pragma unroll
      for (int p = 0; p < 4; ++p) acc[di][dj][p] = 0.0f;

  const int pp0 = pg << 2;
  const float* hbase = hq_cbase(hqA, hqB, b) + sp0 + pp0;
#pragma unroll 4
  for (int ci = 0; ci < 128; ++ci) {
    const float4 h4 = *(const float4*)(hbase + (size_t)ci * HWS);
    const float4 w = wl4[ci][cg];   // (w00, w01, w10, w11)
    acc[0][0][0] += w.x * h4.x; acc[0][0][1] += w.x * h4.y; acc[0][0][2] += w.x * h4.z; acc[0][0][3] += w.x * h4.w;
    acc[0][1][0] += w.y * h4.x; acc[0][1][1] += w.y * h4.y; acc[0][1][2] += w.y * h4.z; acc[0][1][3] += w.y * h4.w;
    acc[1][0][0] += w.z * h4.x; acc[1][0][1] += w.z * h4.y; acc[1][0][2] += w.z * h4.z; acc[1][0][3] += w.z * h4.w;
    acc[1][1][0] += w.w * h4.x; acc[1][1][1] += w.w * h4.y; acc[1][1][2] += w.w * h4.z; acc[1][1][3] += w.w * h4.w;
  }

  const int sp = sp0 + pp0;
  const int yy = sp / 56, xx = sp - yy * 56;
  const int co = cobase + cg;
  const float a = a2[co], c = c2b[co];
#pragma unroll
  for (int di = 0; di < 2; ++di) {
    float4 lo, hi;
    lo.x = fmaxf(acc[di][0][0] * a + c, 0.0f);
    lo.y = fmaxf(acc[di][1][0] * a + c, 0.0f);
    lo.z = fmaxf(acc[di][0][1] * a + c, 0.0f);
    lo.w = fmaxf(acc[di][1][1] * a + c, 0.0f);
    hi.x = fmaxf(acc[di][0][2] * a + c, 0.0f);
    hi.y = fmaxf(acc[di][1][2] * a + c, 0.0f);
    hi.z = fmaxf(acc[di][0][3] * a + c, 0.0f);
    hi.w = fmaxf(acc[di][1][3] * a + c, 0.0f);
    float* o = out + ((size_t)(b * NCI + co) * OHS + (yy * 2 + di)) * OHS + xx * 2;
    *(float4*)o = lo;
    *((float4*)o + 1) = hi;
  }
}

// ---------------- launch --------------------------------------------------------
extern "C" void kernel_launch(void* const* d_in, const int* in_sizes, int n_in,
                              void* d_out, int out_size, void* d_ws, size_t ws_size,
                              hipStream_t stream) {
  (void)in_sizes; (void)n_in; (void)out_size;
  const float* x       = (const float*)d_in[0];
  const float* noise_u = (const float*)d_in[1];
  const float* w1      = (const float*)d_in[2];
  const float* b1      = (const float*)d_in[3];
  const float* g1      = (const float*)d_in[4];
  const float* beta1   = (const float*)d_in[5];
  const float* w4      = (const float*)d_in[6];
  const float* b4      = (const float*)d_in[7];
  const float* g2      = (const float*)d_in[8];
  const float* beta2   = (const float*)d_in[9];

  // d_out doubles as scratch: everything here is consumed before k_deconv writes.
  float*  out   = (float*)d_out;
  double* hpre  = (double*)d_out;                 // NELEM doubles = 102.8 MB
  float*  wT    = out + 2 * (size_t)NELEM;        // float offset 25,690,112
  float*  gp    = wT + WT_SZ;
  double* G     = (double*)(gp + GP_SZ);          // byte offset % 8 == 0
  double* Sh    = G + 16384;
  // scratch high-water: ~30.2M floats << fallback hq tail at 90.3M floats.

  // h_q placement — adaptive on ws_size (deterministic, graph-capture safe).
  float* ws = (float*)d_ws;
  const bool fast = ws_size >= (size_t)NELEM * 4 + 65536;
  float *hqA, *hqB; double* coefd;
  if (fast) {
    hqA   = ws;                                   // chunks 0..30
    hqB   = ws + (size_t)31 * CHUNK;              // chunk 31 (contiguous)
    coefd = (double*)(ws + NELEM);                // NELEM*4 % 8 == 0
  } else {
    hqA   = out + (OUTSZ - (size_t)31 * CHUNK);   // tail of d_out
    hqB   = ws;                                   // chunk 31
    coefd = (double*)(ws + CHUNK);                // CHUNK*4 % 8 == 0
  }
  double* a1  = coefd;            // 128 doubles
  double* c1  = coefd + 128;      // 128 doubles
  float*  a2  = (float*)(coefd + 256);
  float*  c2b = a2 + 256;

  k_wprep<<<dim3((WT_SZ + 255) / 256), dim3(256), 0, stream>>>(w1, wT);
  k_conv1<<<dim3(49, 2, NB), dim3(256), 0, stream>>>(x, noise_u, wT, b1, hpre);
  k_bn1stats<<<dim3(128), dim3(256), 0, stream>>>(hpre, g1, beta1, a1, c1);
  k_bnsig<<<dim3(CHUNK / 256, NB), dim3(256), 0, stream>>>(hpre, a1, c1, noise_u, hqA, hqB);
  k_meanh<<<dim3(128), dim3(256), 0, stream>>>(hqA, hqB, Sh);
  k_gram<<<dim3(256), dim3(256), 0, stream>>>(hqA, hqB, gp);
  k_gram_reduce<<<dim3(64), dim3(256), 0, stream>>>(gp, G);
  k_bn2coef<<<dim3(256), dim3(256), 0, stream>>>(w4, b4, g2, beta2, G, Sh, a2, c2b);
  if (fast) {
    k_deconv<<<dim3(49, 16, NB), dim3(256), 0, stream>>>(hqA, hqB, w4, a2, c2b, out, 0);
  } else {
    for (int b = 0; b < NB; ++b)
      k_deconv<<<dim3(49, 16, 1), dim3(256), 0, stream>>>(hqA, hqB, w4, a2, c2b, out, b);
  }
}